// Round 4
// baseline (390.714 us; speedup 1.0000x reference)
//
#include <hip/hip_runtime.h>
#include <math.h>

typedef unsigned int uint;
typedef unsigned short ushort;

typedef __attribute__((ext_vector_type(8))) __bf16 bf16x8;
typedef __attribute__((ext_vector_type(16))) float floatx16;

#define NFEAT 327680   // 256*1280 feats (bf16)
#define NW    491520   // 128*3840 W (bf16)
// ws: fB bf16[NFEAT] | wB bf16[NW] | stats f32[16] | Aoi f32[128*256]

union U4B8 { uint4 u; bf16x8 b; };

__device__ inline ushort f2b(float f) {
  uint u = __float_as_uint(f);
  u += 0x7fffu + ((u >> 16) & 1u);   // RNE
  return (ushort)(u >> 16);
}
__device__ inline float blo(uint u) { return __uint_as_float(u << 16); }
__device__ inline float bhi(uint u) { return __uint_as_float(u & 0xffff0000u); }

#if __has_builtin(__builtin_amdgcn_cvt_pk_bf16_f32)
typedef __attribute__((ext_vector_type(2))) __bf16 bf16x2;
__device__ inline uint cvtpk(float a, float b) {
  bf16x2 r = __builtin_amdgcn_cvt_pk_bf16_f32(a, b);
  return *(uint*)&r;
}
__device__ inline uint cvtpk_abs(float a, float b) { return cvtpk(fabsf(a), fabsf(b)); }
#else
__device__ inline uint cvtpk(float a, float b) {   // round-half-up fallback
  uint au = __float_as_uint(a) + 0x8000u;
  uint bu = __float_as_uint(b) + 0x8000u;
  return __builtin_amdgcn_perm(bu, au, 0x07060302u);
}
__device__ inline uint cvtpk_abs(float a, float b) { return cvtpk(a, b) & 0x7fff7fffu; }
#endif

// ---------------- prep: fp32 -> bf16, zero stats + Aoi ----------------
__global__ void prep_kernel(const float* __restrict__ feats,
                            const float* __restrict__ W,
                            ushort* __restrict__ fB,
                            ushort* __restrict__ wB,
                            float* __restrict__ stats,
                            float* __restrict__ Aoi) {
  int idx = blockIdx.x * 256 + threadIdx.x;   // 3200*256 = NFEAT+NW
  if (blockIdx.x == 0 && threadIdx.x < 16) stats[threadIdx.x] = 0.0f;
  if (idx < 32768) Aoi[idx] = 0.0f;
  if (idx < NFEAT) fB[idx] = f2b(feats[idx]);
  else             wB[idx - NFEAT] = f2b(W[idx - NFEAT]);
}

// ---------------- A[o,i] = sum_c Wa[o,c]*f[i,c] ----------------
// 32 blocks = 8 i-tiles(32) x 4 k-quarters(320); partial sums atomicAdd'ed
__global__ __launch_bounds__(256, 2) void gemma_kernel(
    const ushort* __restrict__ fB, const ushort* __restrict__ wB,
    float* __restrict__ Aoi) {
  __shared__ float red[4][4096];
  const int tid = threadIdx.x, lane = tid & 63, w = tid >> 6;
  const int i0 = (blockIdx.x >> 2) << 5;
  const int kq = blockIdx.x & 3;
  const int rr = lane & 31, half = lane >> 5;
  floatx16 a4[4];
  #pragma unroll
  for (int ot = 0; ot < 4; ++ot)
    #pragma unroll
    for (int r = 0; r < 16; ++r) a4[ot][r] = 0.0f;
  const int kbase = kq * 320 + w * 80 + half * 8;
  #pragma unroll
  for (int ks = 0; ks < 5; ++ks) {
    const int k = kbase + ks * 16;
    U4B8 bf; bf.u = *(const uint4*)(fB + (i0 + rr) * 1280 + k);
    #pragma unroll
    for (int ot = 0; ot < 4; ++ot) {
      U4B8 af; af.u = *(const uint4*)(wB + (ot * 32 + rr) * 3840 + k);
      a4[ot] = __builtin_amdgcn_mfma_f32_32x32x16_bf16(af.b, bf.b, a4[ot], 0, 0, 0);
    }
  }
  #pragma unroll
  for (int ot = 0; ot < 4; ++ot)
    #pragma unroll
    for (int r = 0; r < 16; ++r) {
      const int orow = (r & 3) + 8 * (r >> 2) + 4 * half;
      red[w][(ot * 32 + orow) * 32 + rr] = a4[ot][r];
    }
  __syncthreads();
  for (int e = tid; e < 4096; e += 256) {
    float s = red[0][e] + red[1][e] + red[2][e] + red[3][e];
    atomicAdd(&Aoi[(e >> 5) * 256 + i0 + (e & 31)], s);
  }
}

// build diff/had B-fragments for one m-tile from fj bits + unpacked fi
__device__ inline void build(const uint4 vj, const float fi8[8], U4B8& d, U4B8& h) {
  uint ju[4] = {vj.x, vj.y, vj.z, vj.w};
  uint* pd = &d.u.x; uint* ph = &h.u.x;
  #pragma unroll
  for (int t = 0; t < 4; ++t) {
    float j0f = blo(ju[t]), j1f = bhi(ju[t]);
    float i0 = fi8[2 * t], i1 = fi8[2 * t + 1];
    pd[t] = cvtpk_abs(i0 - j0f, i1 - j1f);
    ph[t] = cvtpk(i0 * j0f, i1 * j1f);
  }
}

// ---------------- main fused GEMM: diff+had, K=2560, barrier-free ----------------
// X[o,m] = sum Wd|fi-fj| + Wh(fi*fj); epilogue adds A[o,i]+A[o,j]+b[o].
// grid 1024: i = blk>>2, j0 = (blk&3)*64. Block = 128 thr = 2 waves split by o
// (wo = w*64). Wave tile 64o x 64m, acc 2x2x16. Each wave stages its own
// W rows into a PRIVATE LDS double buffer -> no __syncthreads in K-loop.
__global__ __launch_bounds__(128, 2) void gemm_kernel(
    const ushort* __restrict__ fB, const ushort* __restrict__ wB,
    const float* __restrict__ bias, const float* __restrict__ Aoi,
    float* __restrict__ xout, float* __restrict__ stats) {
  __shared__ __align__(16) ushort Wl[2][2][64 * 72];  // [wave][buf][row*72 + term*32 + k]

  const int tid = threadIdx.x;
  const int blk = blockIdx.x;
  const int i_row = blk >> 2;
  const int j0 = (blk & 3) << 6;
  const int lane = tid & 63;
  const int w = tid >> 6;          // 0,1
  const int wo = w << 6;           // o-base 0 or 64
  const int rr = lane & 31;
  const int half = lane >> 5;

  // staging map: s = p*64+lane -> term=s>>8, row=(s&255)>>2, q=s&3  (coalesced)
  const ushort* gptr[8];
  int loff[8];
  #pragma unroll
  for (int p = 0; p < 8; ++p) {
    const int s = p * 64 + lane;
    const int term = s >> 8, rem = s & 255, row = rem >> 2, q = rem & 3;
    gptr[p] = wB + (wo + row) * 3840 + 1280 + term * 1280 + q * 8;
    loff[p] = row * 72 + term * 32 + q * 8;
  }

  const ushort* fip  = fB + i_row * 1280 + half * 8;
  const ushort* fj0p = fB + (j0 + rr) * 1280 + half * 8;
  const ushort* fj1p = fB + (j0 + 32 + rr) * 1280 + half * 8;

  floatx16 acc[2][2];  // [ot][mt]
  #pragma unroll
  for (int a = 0; a < 2; ++a)
    #pragma unroll
    for (int b = 0; b < 2; ++b)
      #pragma unroll
      for (int r = 0; r < 16; ++r) acc[a][b][r] = 0.0f;

  ushort* wbuf[2] = {&Wl[w][0][0], &Wl[w][1][0]};

  // prologue: stage chunk 0 into buf 0 (own-wave lgkmcnt ordering, no barrier)
  {
    uint4 v[8];
    #pragma unroll
    for (int p = 0; p < 8; ++p) v[p] = *(const uint4*)(gptr[p]);
    #pragma unroll
    for (int p = 0; p < 8; ++p) *(uint4*)(wbuf[0] + loff[p]) = v[p];
  }
  uint4 vi[2], vj0[2], vj1[2];
  #pragma unroll
  for (int st = 0; st < 2; ++st) {
    vi[st]  = *(const uint4*)(fip  + st * 16);
    vj0[st] = *(const uint4*)(fj0p + st * 16);
    vj1[st] = *(const uint4*)(fj1p + st * 16);
  }

  for (int cc = 0; cc < 40; ++cc) {
    const int cur = cc & 1;
    const ushort* Wc = wbuf[cur];
    uint4 wn[8], vin[2], vj0n[2], vj1n[2];
    if (cc < 39) {
      const int cn = (cc + 1) << 5;
      #pragma unroll
      for (int p = 0; p < 8; ++p) wn[p] = *(const uint4*)(gptr[p] + cn);
      #pragma unroll
      for (int st = 0; st < 2; ++st) {
        vin[st]  = *(const uint4*)(fip  + cn + st * 16);
        vj0n[st] = *(const uint4*)(fj0p + cn + st * 16);
        vj1n[st] = *(const uint4*)(fj1p + cn + st * 16);
      }
    }
    #pragma unroll
    for (int st = 0; st < 2; ++st) {
      float fi8[8];
      {
        uint iu[4] = {vi[st].x, vi[st].y, vi[st].z, vi[st].w};
        #pragma unroll
        for (int t = 0; t < 4; ++t) { fi8[2*t] = blo(iu[t]); fi8[2*t+1] = bhi(iu[t]); }
      }
      U4B8 dfr[2], hfr[2];
      build(vj0[st], fi8, dfr[0], hfr[0]);
      build(vj1[st], fi8, dfr[1], hfr[1]);
      #pragma unroll
      for (int ot = 0; ot < 2; ++ot) {
        const int rb = (ot * 32 + rr) * 72 + st * 16 + half * 8;
        bf16x8 ad = *(const bf16x8*)(Wc + rb);
        bf16x8 ah = *(const bf16x8*)(Wc + rb + 32);
        acc[ot][0] = __builtin_amdgcn_mfma_f32_32x32x16_bf16(ad, dfr[0].b, acc[ot][0], 0, 0, 0);
        acc[ot][1] = __builtin_amdgcn_mfma_f32_32x32x16_bf16(ad, dfr[1].b, acc[ot][1], 0, 0, 0);
        acc[ot][0] = __builtin_amdgcn_mfma_f32_32x32x16_bf16(ah, hfr[0].b, acc[ot][0], 0, 0, 0);
        acc[ot][1] = __builtin_amdgcn_mfma_f32_32x32x16_bf16(ah, hfr[1].b, acc[ot][1], 0, 0, 0);
      }
      // stage next chunk between the two k-substeps so st=1 MFMAs cover writes
      if (st == 0 && cc < 39) {
        ushort* Wn = wbuf[cur ^ 1];
        #pragma unroll
        for (int p = 0; p < 8; ++p) *(uint4*)(Wn + loff[p]) = wn[p];
      }
    }
    if (cc < 39) {
      #pragma unroll
      for (int st = 0; st < 2; ++st) {
        vi[st] = vin[st]; vj0[st] = vj0n[st]; vj1[st] = vj1n[st];
      }
    }
  }

  // epilogue: add A[o,i]+A[o,j]+b[o], store, group stats
  float gs[2][2] = {{0.f, 0.f}, {0.f, 0.f}};
  float gq[2][2] = {{0.f, 0.f}, {0.f, 0.f}};
  const int m0 = i_row * 256 + j0;
  #pragma unroll
  for (int ot = 0; ot < 2; ++ot) {
    #pragma unroll
    for (int r = 0; r < 16; ++r) {
      const int orow = (r & 3) + 8 * (r >> 2) + 4 * half;  // D row map (m74/m101)
      const int o = wo + ot * 32 + orow;
      const float base_i = Aoi[o * 256 + i_row] + bias[o];
      const float* aj = Aoi + o * 256 + j0;
      #pragma unroll
      for (int mt = 0; mt < 2; ++mt) {
        const int j = mt * 32 + rr;
        float x = acc[ot][mt][r] + base_i + aj[j];
        xout[o * 65536 + m0 + j] = x;
        gs[ot][r >> 3] += x;
        gq[ot][r >> 3] += x * x;
      }
    }
  }
  #pragma unroll
  for (int ot = 0; ot < 2; ++ot) {
    #pragma unroll
    for (int rg = 0; rg < 2; ++rg) {
      float s = gs[ot][rg], qv = gq[ot][rg];
      for (int off = 32; off > 0; off >>= 1) {
        s += __shfl_xor(s, off, 64);
        qv += __shfl_xor(qv, off, 64);
      }
      if (lane == 0) {
        const int g = (wo >> 4) + ot * 2 + rg;
        atomicAdd(&stats[g], s);
        atomicAdd(&stats[8 + g], qv);
      }
    }
  }
}

// ---------------- groupnorm + exact gelu, in place ----------------
__global__ void norm_kernel(float* __restrict__ xout,
                            const float* __restrict__ stats,
                            const float* __restrict__ gamma,
                            const float* __restrict__ beta) {
  const int idx = blockIdx.x * 256 + threadIdx.x;
  const int e = idx << 2;
  const int o = e >> 16;
  const int g = o >> 4;
  const float invN = 1.0f / 1048576.0f;  // 16*65536 per group
  const float mean = stats[g] * invN;
  const float var = stats[8 + g] * invN - mean * mean;
  const float inv = rsqrtf(var + 1e-5f);
  const float ga = gamma[o], be = beta[o];
  float4 v = *(float4*)(xout + e);
  float* pv = &v.x;
  #pragma unroll
  for (int t = 0; t < 4; ++t) {
    float xn = (pv[t] - mean) * inv * ga + be;
    pv[t] = 0.5f * xn * (1.0f + erff(xn * 0.70710678118654752f));
  }
  *(float4*)(xout + e) = v;
}

extern "C" void kernel_launch(void* const* d_in, const int* in_sizes, int n_in,
                              void* d_out, int out_size, void* d_ws, size_t ws_size,
                              hipStream_t stream) {
  const float* feats = (const float*)d_in[0];
  const float* W     = (const float*)d_in[1];
  const float* bias  = (const float*)d_in[2];
  const float* gamma = (const float*)d_in[3];
  const float* beta  = (const float*)d_in[4];
  float* out = (float*)d_out;

  ushort* fB = (ushort*)d_ws;
  ushort* wB = fB + NFEAT;
  float* stats = (float*)(wB + NW);
  float* Aoi = stats + 16;

  prep_kernel<<<3200, 256, 0, stream>>>(feats, W, fB, wB, stats, Aoi);
  gemma_kernel<<<32, 256, 0, stream>>>(fB, wB, Aoi);
  gemm_kernel<<<1024, 128, 0, stream>>>(fB, wB, bias, Aoi, out, stats);
  norm_kernel<<<8192, 256, 0, stream>>>(out, stats, gamma, beta);
}

// Round 5
// 185.577 us; speedup vs baseline: 2.1054x; 2.1054x over previous
//
#include <hip/hip_runtime.h>
#include <math.h>

typedef unsigned int uint;
typedef unsigned short ushort;

typedef __attribute__((ext_vector_type(8))) __bf16 bf16x8;
typedef __attribute__((ext_vector_type(16))) float floatx16;

#define NFEAT 327680   // 256*1280 feats (bf16)
#define NW    491520   // 128*3840 W (bf16)
// ws: fB bf16[NFEAT] | wB bf16[NW] | stats f32[16] | Aoi f32[128*256]

union U4B8 { uint4 u; bf16x8 b; };

__device__ inline ushort f2b(float f) {
  uint u = __float_as_uint(f);
  u += 0x7fffu + ((u >> 16) & 1u);   // RNE
  return (ushort)(u >> 16);
}
__device__ inline float blo(uint u) { return __uint_as_float(u << 16); }
__device__ inline float bhi(uint u) { return __uint_as_float(u & 0xffff0000u); }

#if __has_builtin(__builtin_amdgcn_cvt_pk_bf16_f32)
typedef __attribute__((ext_vector_type(2))) __bf16 bf16x2;
__device__ inline uint cvtpk(float a, float b) {
  bf16x2 r = __builtin_amdgcn_cvt_pk_bf16_f32(a, b);
  return *(uint*)&r;
}
__device__ inline uint cvtpk_abs(float a, float b) { return cvtpk(fabsf(a), fabsf(b)); }
#else
__device__ inline uint cvtpk(float a, float b) {   // round-half-up fallback
  uint au = __float_as_uint(a) + 0x8000u;
  uint bu = __float_as_uint(b) + 0x8000u;
  return __builtin_amdgcn_perm(bu, au, 0x07060302u);
}
__device__ inline uint cvtpk_abs(float a, float b) { return cvtpk(a, b) & 0x7fff7fffu; }
#endif

// async global->LDS DMA, 16B per lane; lds dest is WAVE-UNIFORM base (+lane*16 implicit)
__device__ inline void async16(const ushort* g, ushort* l) {
  __builtin_amdgcn_global_load_lds((const __attribute__((address_space(1))) uint*)g,
                                   (__attribute__((address_space(3))) uint*)l, 16, 0, 0);
}

// ---------------- prep: fp32 -> bf16, zero stats + Aoi ----------------
__global__ void prep_kernel(const float* __restrict__ feats,
                            const float* __restrict__ W,
                            ushort* __restrict__ fB,
                            ushort* __restrict__ wB,
                            float* __restrict__ stats,
                            float* __restrict__ Aoi) {
  int idx = blockIdx.x * 256 + threadIdx.x;   // 3200*256 = NFEAT+NW
  if (blockIdx.x == 0 && threadIdx.x < 16) stats[threadIdx.x] = 0.0f;
  if (idx < 32768) Aoi[idx] = 0.0f;
  if (idx < NFEAT) fB[idx] = f2b(feats[idx]);
  else             wB[idx - NFEAT] = f2b(W[idx - NFEAT]);
}

// ---------------- A[o,i] = sum_c Wa[o,c]*f[i,c] ----------------
// 32 blocks = 8 i-tiles(32) x 4 k-quarters(320); partials atomicAdd'ed
__global__ __launch_bounds__(256, 2) void gemma_kernel(
    const ushort* __restrict__ fB, const ushort* __restrict__ wB,
    float* __restrict__ Aoi) {
  __shared__ float red[4][4096];
  const int tid = threadIdx.x, lane = tid & 63, w = tid >> 6;
  const int i0 = (blockIdx.x >> 2) << 5;
  const int kq = blockIdx.x & 3;
  const int rr = lane & 31, half = lane >> 5;
  floatx16 a4[4];
  #pragma unroll
  for (int ot = 0; ot < 4; ++ot)
    #pragma unroll
    for (int r = 0; r < 16; ++r) a4[ot][r] = 0.0f;
  const int kbase = kq * 320 + w * 80 + half * 8;
  #pragma unroll
  for (int ks = 0; ks < 5; ++ks) {
    const int k = kbase + ks * 16;
    U4B8 bf; bf.u = *(const uint4*)(fB + (i0 + rr) * 1280 + k);
    #pragma unroll
    for (int ot = 0; ot < 4; ++ot) {
      U4B8 af; af.u = *(const uint4*)(wB + (ot * 32 + rr) * 3840 + k);
      a4[ot] = __builtin_amdgcn_mfma_f32_32x32x16_bf16(af.b, bf.b, a4[ot], 0, 0, 0);
    }
  }
  #pragma unroll
  for (int ot = 0; ot < 4; ++ot)
    #pragma unroll
    for (int r = 0; r < 16; ++r) {
      const int orow = (r & 3) + 8 * (r >> 2) + 4 * half;
      red[w][(ot * 32 + orow) * 32 + rr] = a4[ot][r];
    }
  __syncthreads();
  for (int e = tid; e < 4096; e += 256) {
    float s = red[0][e] + red[1][e] + red[2][e] + red[3][e];
    atomicAdd(&Aoi[(e >> 5) * 256 + i0 + (e & 31)], s);
  }
}

// build diff/had B-fragments from fj bits + unpacked fi
__device__ inline void build(const uint4 vj, const float fi8[8], U4B8& d, U4B8& h) {
  uint ju[4] = {vj.x, vj.y, vj.z, vj.w};
  uint* pd = &d.u.x; uint* ph = &h.u.x;
  #pragma unroll
  for (int t = 0; t < 4; ++t) {
    float j0f = blo(ju[t]), j1f = bhi(ju[t]);
    float i0 = fi8[2 * t], i1 = fi8[2 * t + 1];
    pd[t] = cvtpk_abs(i0 - j0f, i1 - j1f);
    ph[t] = cvtpk(i0 * j0f, i1 * j1f);
  }
}

// ---------------- main fused GEMM: diff+had, K=2560 ----------------
// R3 skeleton: grid 1024 (i=blk>>2, j0=(blk&3)*64), 256 thr = 4 waves 2x2
// (wo=(w>>1)*64, wm=(w&1)*32), wave tile 64o x 32m, 1 barrier/chunk.
// NEW: W staged via global_load_lds (async DMA, width 16) into a stride-64
// XOR-octet-swizzled LDS dbuf (32 KB); launch_bounds(256,5) -> 5 blocks/CU,
// 20 waves/CU. B-fragments built in registers; fi/fj loaded in-chunk.
__global__ __launch_bounds__(256, 5) void gemm_kernel(
    const ushort* __restrict__ fB, const ushort* __restrict__ wB,
    const float* __restrict__ bias, const float* __restrict__ Aoi,
    float* __restrict__ xout, float* __restrict__ stats) {
  // LDS: [buf][row(128)][slot(8)*8ush], slot = octet ^ (row&7); octet = term*4+st*2+half
  __shared__ __align__(16) ushort Wl[2 * 128 * 64];  // 32 KB

  const int tid = threadIdx.x;
  const int blk = blockIdx.x;
  const int i_row = blk >> 2;
  const int j0 = (blk & 3) << 6;
  const int lane = tid & 63;
  const int w = tid >> 6;
  const int wo = (w >> 1) << 6;
  const int wm = (w & 1) << 5;
  const int rr = lane & 31;
  const int half = lane >> 5;
  const int rr7 = lane & 7;

  // DMA source: 4 per wave. DMA (w,p) fills rows [ (w*4+p)*8, +8 ) x 8 slots.
  // lane l -> row = seg*8 + (l>>3), slot = l&7, global octet g = slot ^ (l>>3)
  const ushort* gsrc[4];
  #pragma unroll
  for (int p = 0; p < 4; ++p) {
    const int seg = w * 4 + p;
    const int row = seg * 8 + (lane >> 3);
    const int g = (lane & 7) ^ (lane >> 3);
    gsrc[p] = wB + row * 3840 + 1280 + (g >> 2) * 1280 + (g & 3) * 8;
  }

  const ushort* fip = fB + i_row * 1280 + half * 8;
  const ushort* fjp = fB + (j0 + wm + rr) * 1280 + half * 8;

  floatx16 acc[2];
  #pragma unroll
  for (int a = 0; a < 2; ++a)
    #pragma unroll
    for (int r = 0; r < 16; ++r) acc[a][r] = 0.0f;

  // prologue: DMA chunk 0 into buf 0
  #pragma unroll
  for (int p = 0; p < 4; ++p)
    async16(gsrc[p], &Wl[(w * 4 + p) * 512]);
  __syncthreads();

  for (int cc = 0; cc < 40; ++cc) {
    const int cur = cc & 1;
    // issue DMA for next chunk into other buffer (readers of it finished
    // before the PREVIOUS barrier; completion enforced by vmcnt drain at
    // this chunk's end barrier)
    if (cc < 39) {
      const int cn = (cc + 1) << 5;
      #pragma unroll
      for (int p = 0; p < 4; ++p)
        async16(gsrc[p] + cn, &Wl[(cur ^ 1) * 8192 + (w * 4 + p) * 512]);
    }
    const ushort* Wc = &Wl[cur * 8192];
    #pragma unroll
    for (int st = 0; st < 2; ++st) {
      const int c = (cc << 5) + (st << 4);
      const uint4 vi = *(const uint4*)(fip + c);
      const uint4 vj = *(const uint4*)(fjp + c);
      float fi8[8];
      {
        uint iu[4] = {vi.x, vi.y, vi.z, vi.w};
        #pragma unroll
        for (int t = 0; t < 4; ++t) { fi8[2*t] = blo(iu[t]); fi8[2*t+1] = bhi(iu[t]); }
      }
      U4B8 dfr, hfr;
      build(vj, fi8, dfr, hfr);
      const int g0 = (st << 1) + half;        // term-0 octet (0..3)
      #pragma unroll
      for (int ot = 0; ot < 2; ++ot) {
        const int rowb = (wo + ot * 32 + rr) << 6;
        bf16x8 ad = *(const bf16x8*)(Wc + rowb + ((g0 ^ rr7) << 3));
        bf16x8 ah = *(const bf16x8*)(Wc + rowb + (((g0 + 4) ^ rr7) << 3));
        acc[ot] = __builtin_amdgcn_mfma_f32_32x32x16_bf16(ad, dfr.b, acc[ot], 0, 0, 0);
        acc[ot] = __builtin_amdgcn_mfma_f32_32x32x16_bf16(ah, hfr.b, acc[ot], 0, 0, 0);
      }
    }
    __syncthreads();
  }

  // epilogue: add A[o,i]+A[o,j]+b[o], store, group stats
  float gs[2][2] = {{0.f, 0.f}, {0.f, 0.f}};
  float gq[2][2] = {{0.f, 0.f}, {0.f, 0.f}};
  const int jg = j0 + wm + rr;
  const int mglob = i_row * 256 + jg;
  #pragma unroll
  for (int ot = 0; ot < 2; ++ot) {
    #pragma unroll
    for (int r = 0; r < 16; ++r) {
      const int orow = (r & 3) + 8 * (r >> 2) + 4 * half;  // D row map (m74/m101)
      const int o = wo + ot * 32 + orow;
      float x = acc[ot][r] + Aoi[o * 256 + i_row] + Aoi[o * 256 + jg] + bias[o];
      xout[o * 65536 + mglob] = x;
      gs[ot][r >> 3] += x;
      gq[ot][r >> 3] += x * x;
    }
  }
  float* sred = (float*)Wl;
  if (tid < 16) sred[tid] = 0.0f;
  __syncthreads();
  #pragma unroll
  for (int ot = 0; ot < 2; ++ot) {
    #pragma unroll
    for (int rg = 0; rg < 2; ++rg) {
      float s = gs[ot][rg], qv = gq[ot][rg];
      for (int off = 32; off > 0; off >>= 1) {
        s += __shfl_xor(s, off, 64);
        qv += __shfl_xor(qv, off, 64);
      }
      if (lane == 0) {
        const int g = (wo >> 4) + ot * 2 + rg;
        atomicAdd(&sred[g], s);
        atomicAdd(&sred[8 + g], qv);
      }
    }
  }
  __syncthreads();
  if (tid < 16) atomicAdd(&stats[tid], sred[tid]);
}

// ---------------- groupnorm + exact gelu, in place ----------------
__global__ void norm_kernel(float* __restrict__ xout,
                            const float* __restrict__ stats,
                            const float* __restrict__ gamma,
                            const float* __restrict__ beta) {
  const int idx = blockIdx.x * 256 + threadIdx.x;
  const int e = idx << 2;
  const int o = e >> 16;
  const int g = o >> 4;
  const float invN = 1.0f / 1048576.0f;  // 16*65536 per group
  const float mean = stats[g] * invN;
  const float var = stats[8 + g] * invN - mean * mean;
  const float inv = rsqrtf(var + 1e-5f);
  const float ga = gamma[o], be = beta[o];
  float4 v = *(float4*)(xout + e);
  float* pv = &v.x;
  #pragma unroll
  for (int t = 0; t < 4; ++t) {
    float xn = (pv[t] - mean) * inv * ga + be;
    pv[t] = 0.5f * xn * (1.0f + erff(xn * 0.70710678118654752f));
  }
  *(float4*)(xout + e) = v;
}

extern "C" void kernel_launch(void* const* d_in, const int* in_sizes, int n_in,
                              void* d_out, int out_size, void* d_ws, size_t ws_size,
                              hipStream_t stream) {
  const float* feats = (const float*)d_in[0];
  const float* W     = (const float*)d_in[1];
  const float* bias  = (const float*)d_in[2];
  const float* gamma = (const float*)d_in[3];
  const float* beta  = (const float*)d_in[4];
  float* out = (float*)d_out;

  ushort* fB = (ushort*)d_ws;
  ushort* wB = fB + NFEAT;
  float* stats = (float*)(wB + NW);
  float* Aoi = stats + 16;

  prep_kernel<<<3200, 256, 0, stream>>>(feats, W, fB, wB, stats, Aoi);
  gemma_kernel<<<32, 256, 0, stream>>>(fB, wB, Aoi);
  gemm_kernel<<<1024, 256, 0, stream>>>(fB, wB, bias, Aoi, out, stats);
  norm_kernel<<<8192, 256, 0, stream>>>(out, stats, gamma, beta);
}

// Round 6
// 179.497 us; speedup vs baseline: 2.1767x; 1.0339x over previous
//
#include <hip/hip_runtime.h>
#include <math.h>

typedef unsigned int uint;
typedef unsigned short ushort;

typedef __attribute__((ext_vector_type(8))) __bf16 bf16x8;
typedef __attribute__((ext_vector_type(16))) float floatx16;

#define NFEAT 327680   // 256*1280 feats (bf16)
#define NW    491520   // 128*3840 W (bf16)
// ws: fB bf16[NFEAT] | wB bf16[NW] | stats f32[16] | Aoi f32[128*256]

union U4B8 { uint4 u; bf16x8 b; };

__device__ inline ushort f2b(float f) {
  uint u = __float_as_uint(f);
  u += 0x7fffu + ((u >> 16) & 1u);   // RNE
  return (ushort)(u >> 16);
}
__device__ inline float blo(uint u) { return __uint_as_float(u << 16); }
__device__ inline float bhi(uint u) { return __uint_as_float(u & 0xffff0000u); }

#if __has_builtin(__builtin_amdgcn_cvt_pk_bf16_f32)
typedef __attribute__((ext_vector_type(2))) __bf16 bf16x2;
__device__ inline uint cvtpk(float a, float b) {
  bf16x2 r = __builtin_amdgcn_cvt_pk_bf16_f32(a, b);
  return *(uint*)&r;
}
__device__ inline uint cvtpk_abs(float a, float b) { return cvtpk(fabsf(a), fabsf(b)); }
#else
__device__ inline uint cvtpk(float a, float b) {   // round-half-up fallback
  uint au = __float_as_uint(a) + 0x8000u;
  uint bu = __float_as_uint(b) + 0x8000u;
  return __builtin_amdgcn_perm(bu, au, 0x07060302u);
}
__device__ inline uint cvtpk_abs(float a, float b) { return cvtpk(a, b) & 0x7fff7fffu; }
#endif

// async global->LDS DMA, 16B/lane; lds dest wave-uniform base (+lane*16 implicit)
__device__ inline void async16(const ushort* g, ushort* l) {
  __builtin_amdgcn_global_load_lds((const __attribute__((address_space(1))) uint*)g,
                                   (__attribute__((address_space(3))) uint*)l, 16, 0, 0);
}

// ---------------- prep: fp32 -> bf16, zero stats + Aoi ----------------
__global__ void prep_kernel(const float* __restrict__ feats,
                            const float* __restrict__ W,
                            ushort* __restrict__ fB,
                            ushort* __restrict__ wB,
                            float* __restrict__ stats,
                            float* __restrict__ Aoi) {
  int idx = blockIdx.x * 256 + threadIdx.x;   // 3200*256 = NFEAT+NW
  if (blockIdx.x == 0 && threadIdx.x < 16) stats[threadIdx.x] = 0.0f;
  if (idx < 32768) Aoi[idx] = 0.0f;
  if (idx < NFEAT) fB[idx] = f2b(feats[idx]);
  else             wB[idx - NFEAT] = f2b(W[idx - NFEAT]);
}

// ---------------- A[o,i] = sum_c Wa[o,c]*f[i,c] ----------------
__global__ __launch_bounds__(256, 2) void gemma_kernel(
    const ushort* __restrict__ fB, const ushort* __restrict__ wB,
    float* __restrict__ Aoi) {
  __shared__ float red[4][4096];
  const int tid = threadIdx.x, lane = tid & 63, w = tid >> 6;
  const int i0 = (blockIdx.x >> 2) << 5;
  const int kq = blockIdx.x & 3;
  const int rr = lane & 31, half = lane >> 5;
  floatx16 a4[4];
  #pragma unroll
  for (int ot = 0; ot < 4; ++ot)
    #pragma unroll
    for (int r = 0; r < 16; ++r) a4[ot][r] = 0.0f;
  const int kbase = kq * 320 + w * 80 + half * 8;
  #pragma unroll
  for (int ks = 0; ks < 5; ++ks) {
    const int k = kbase + ks * 16;
    U4B8 bf; bf.u = *(const uint4*)(fB + (i0 + rr) * 1280 + k);
    #pragma unroll
    for (int ot = 0; ot < 4; ++ot) {
      U4B8 af; af.u = *(const uint4*)(wB + (ot * 32 + rr) * 3840 + k);
      a4[ot] = __builtin_amdgcn_mfma_f32_32x32x16_bf16(af.b, bf.b, a4[ot], 0, 0, 0);
    }
  }
  #pragma unroll
  for (int ot = 0; ot < 4; ++ot)
    #pragma unroll
    for (int r = 0; r < 16; ++r) {
      const int orow = (r & 3) + 8 * (r >> 2) + 4 * half;
      red[w][(ot * 32 + orow) * 32 + rr] = a4[ot][r];
    }
  __syncthreads();
  for (int e = tid; e < 4096; e += 256) {
    float s = red[0][e] + red[1][e] + red[2][e] + red[3][e];
    atomicAdd(&Aoi[(e >> 5) * 256 + i0 + (e & 31)], s);
  }
}

// build diff/had B-fragments from fj bits + unpacked fi
__device__ inline void build(const uint4 vj, const float fi8[8], U4B8& d, U4B8& h) {
  uint ju[4] = {vj.x, vj.y, vj.z, vj.w};
  uint* pd = &d.u.x; uint* ph = &h.u.x;
  #pragma unroll
  for (int t = 0; t < 4; ++t) {
    float j0f = blo(ju[t]), j1f = bhi(ju[t]);
    float i0 = fi8[2 * t], i1 = fi8[2 * t + 1];
    pd[t] = cvtpk_abs(i0 - j0f, i1 - j1f);
    ph[t] = cvtpk(i0 * j0f, i1 * j1f);
  }
}

// ---------------- main fused GEMM: diff+had, K=2560 ----------------
// R5 skeleton (grid 1024, 4 waves 2x2, wave 64o x 32m, DMA W staging, XOR-
// swizzled 32 KB LDS dbuf). NEW: raw s_barrier + s_waitcnt vmcnt(4) per chunk
// instead of __syncthreads -- retires exactly the 4 DMAs (in-order), leaves
// the 4 fi/fj prefetch loads in flight across the barrier. Issue order pinned
// [DMA x4][fi/fj loads x4] via sched_barrier(0) points.
__global__ __launch_bounds__(256, 5) void gemm_kernel(
    const ushort* __restrict__ fB, const ushort* __restrict__ wB,
    const float* __restrict__ bias, const float* __restrict__ Aoi,
    float* __restrict__ xout, float* __restrict__ stats) {
  // LDS: [buf][row(128)][slot(8)*8ush], slot = octet ^ (row&7); octet = term*4+st*2+half
  __shared__ __align__(16) ushort Wl[2 * 128 * 64];  // 32 KB

  const int tid = threadIdx.x;
  const int blk = blockIdx.x;
  const int i_row = blk >> 2;
  const int j0 = (blk & 3) << 6;
  const int lane = tid & 63;
  const int w = tid >> 6;
  const int wo = (w >> 1) << 6;
  const int wm = (w & 1) << 5;
  const int rr = lane & 31;
  const int half = lane >> 5;
  const int rr7 = lane & 7;

  // DMA source: 4 per wave; DMA (w,p) fills rows [(w*4+p)*8, +8) x 8 slots
  const ushort* gsrc[4];
  #pragma unroll
  for (int p = 0; p < 4; ++p) {
    const int seg = w * 4 + p;
    const int row = seg * 8 + (lane >> 3);
    const int g = (lane & 7) ^ (lane >> 3);
    gsrc[p] = wB + row * 3840 + 1280 + (g >> 2) * 1280 + (g & 3) * 8;
  }

  const ushort* fip = fB + i_row * 1280 + half * 8;
  const ushort* fjp = fB + (j0 + wm + rr) * 1280 + half * 8;

  floatx16 acc[2];
  #pragma unroll
  for (int a = 0; a < 2; ++a)
    #pragma unroll
    for (int r = 0; r < 16; ++r) acc[a][r] = 0.0f;

  // prologue: DMA chunk 0 into buf 0, prefetch fi/fj chunk 0
  #pragma unroll
  for (int p = 0; p < 4; ++p)
    async16(gsrc[p], &Wl[(w * 4 + p) * 512]);
  uint4 vi[2], vj[2];
  #pragma unroll
  for (int st = 0; st < 2; ++st) {
    vi[st] = *(const uint4*)(fip + st * 16);
    vj[st] = *(const uint4*)(fjp + st * 16);
  }
  __syncthreads();   // one full drain at prologue is fine

  for (int cc = 0; cc < 40; ++cc) {
    const ushort* Wc = &Wl[(cc & 1) * 8192];
    uint4 vin[2], vjn[2];
    if (cc < 39) {
      const int cn = (cc + 1) << 5;
      #pragma unroll
      for (int p = 0; p < 4; ++p)
        async16(gsrc[p] + cn, &Wl[((cc & 1) ^ 1) * 8192 + (w * 4 + p) * 512]);
      __builtin_amdgcn_sched_barrier(0);   // pin: DMAs issue first
      #pragma unroll
      for (int st = 0; st < 2; ++st) {
        vin[st] = *(const uint4*)(fip + cn + st * 16);
        vjn[st] = *(const uint4*)(fjp + cn + st * 16);
      }
      __builtin_amdgcn_sched_barrier(0);   // pin: loads after DMAs, before compute
    }
    #pragma unroll
    for (int st = 0; st < 2; ++st) {
      float fi8[8];
      {
        uint iu[4] = {vi[st].x, vi[st].y, vi[st].z, vi[st].w};
        #pragma unroll
        for (int t = 0; t < 4; ++t) { fi8[2*t] = blo(iu[t]); fi8[2*t+1] = bhi(iu[t]); }
      }
      U4B8 dfr, hfr;
      build(vj[st], fi8, dfr, hfr);
      const int g0 = (st << 1) + half;        // term-0 octet (0..3)
      #pragma unroll
      for (int ot = 0; ot < 2; ++ot) {
        const int rowb = (wo + ot * 32 + rr) << 6;
        bf16x8 ad = *(const bf16x8*)(Wc + rowb + ((g0 ^ rr7) << 3));
        bf16x8 ah = *(const bf16x8*)(Wc + rowb + (((g0 + 4) ^ rr7) << 3));
        acc[ot] = __builtin_amdgcn_mfma_f32_32x32x16_bf16(ad, dfr.b, acc[ot], 0, 0, 0);
        acc[ot] = __builtin_amdgcn_mfma_f32_32x32x16_bf16(ah, hfr.b, acc[ot], 0, 0, 0);
      }
    }
    if (cc < 39) {
      __builtin_amdgcn_sched_barrier(0);       // keep compute (ds_reads) above
      __builtin_amdgcn_s_waitcnt(0x0F74);      // vmcnt(4): retire the 4 DMAs only
      __builtin_amdgcn_s_barrier();
      __builtin_amdgcn_sched_barrier(0);       // nothing hoists above barrier
      __asm__ volatile("" ::: "memory");       // no LDS value caching across it
      #pragma unroll
      for (int st = 0; st < 2; ++st) { vi[st] = vin[st]; vj[st] = vjn[st]; }
    }
  }

  // epilogue: add A[o,i]+A[o,j]+b[o], store, group stats
  float gs[2][2] = {{0.f, 0.f}, {0.f, 0.f}};
  float gq[2][2] = {{0.f, 0.f}, {0.f, 0.f}};
  const int jg = j0 + wm + rr;
  const int mglob = i_row * 256 + jg;
  #pragma unroll
  for (int ot = 0; ot < 2; ++ot) {
    #pragma unroll
    for (int r = 0; r < 16; ++r) {
      const int orow = (r & 3) + 8 * (r >> 2) + 4 * half;  // D row map (m74/m101)
      const int o = wo + ot * 32 + orow;
      float x = acc[ot][r] + Aoi[o * 256 + i_row] + Aoi[o * 256 + jg] + bias[o];
      xout[o * 65536 + mglob] = x;
      gs[ot][r >> 3] += x;
      gq[ot][r >> 3] += x * x;
    }
  }
  __syncthreads();   // full drain before LDS reuse
  float* sred = (float*)Wl;
  if (tid < 16) sred[tid] = 0.0f;
  __syncthreads();
  #pragma unroll
  for (int ot = 0; ot < 2; ++ot) {
    #pragma unroll
    for (int rg = 0; rg < 2; ++rg) {
      float s = gs[ot][rg], qv = gq[ot][rg];
      for (int off = 32; off > 0; off >>= 1) {
        s += __shfl_xor(s, off, 64);
        qv += __shfl_xor(qv, off, 64);
      }
      if (lane == 0) {
        const int g = (wo >> 4) + ot * 2 + rg;
        atomicAdd(&sred[g], s);
        atomicAdd(&sred[8 + g], qv);
      }
    }
  }
  __syncthreads();
  if (tid < 16) atomicAdd(&stats[tid], sred[tid]);
}

// ---------------- groupnorm + exact gelu, in place ----------------
__global__ void norm_kernel(float* __restrict__ xout,
                            const float* __restrict__ stats,
                            const float* __restrict__ gamma,
                            const float* __restrict__ beta) {
  const int idx = blockIdx.x * 256 + threadIdx.x;
  const int e = idx << 2;
  const int o = e >> 16;
  const int g = o >> 4;
  const float invN = 1.0f / 1048576.0f;  // 16*65536 per group
  const float mean = stats[g] * invN;
  const float var = stats[8 + g] * invN - mean * mean;
  const float inv = rsqrtf(var + 1e-5f);
  const float ga = gamma[o], be = beta[o];
  float4 v = *(float4*)(xout + e);
  float* pv = &v.x;
  #pragma unroll
  for (int t = 0; t < 4; ++t) {
    float xn = (pv[t] - mean) * inv * ga + be;
    pv[t] = 0.5f * xn * (1.0f + erff(xn * 0.70710678118654752f));
  }
  *(float4*)(xout + e) = v;
}

extern "C" void kernel_launch(void* const* d_in, const int* in_sizes, int n_in,
                              void* d_out, int out_size, void* d_ws, size_t ws_size,
                              hipStream_t stream) {
  const float* feats = (const float*)d_in[0];
  const float* W     = (const float*)d_in[1];
  const float* bias  = (const float*)d_in[2];
  const float* gamma = (const float*)d_in[3];
  const float* beta  = (const float*)d_in[4];
  float* out = (float*)d_out;

  ushort* fB = (ushort*)d_ws;
  ushort* wB = fB + NFEAT;
  float* stats = (float*)(wB + NW);
  float* Aoi = stats + 16;

  prep_kernel<<<3200, 256, 0, stream>>>(feats, W, fB, wB, stats, Aoi);
  gemma_kernel<<<32, 256, 0, stream>>>(fB, wB, Aoi);
  gemm_kernel<<<1024, 256, 0, stream>>>(fB, wB, bias, Aoi, out, stats);
  norm_kernel<<<8192, 256, 0, stream>>>(out, stats, gamma, beta);
}